// Round 10
// baseline (192.506 us; speedup 1.0000x reference)
//
#include <hip/hip_runtime.h>

constexpr int VOL = 32 * 32 * 32 * 32;   // 1048576 sites
constexpr float KAPPA = 0.1f;            // kappa/u0
constexpr int TSTEP = 4;                 // t-slices walked per block

struct alignas(8) F2 { float x, y; };
using f2v = __attribute__((ext_vector_type(2))) float;

__device__ __forceinline__ F2 operator+(F2 a, F2 b) { return F2{a.x + b.x, a.y + b.y}; }
__device__ __forceinline__ F2 operator-(F2 a, F2 b) { return F2{a.x - b.x, a.y - b.y}; }
__device__ __forceinline__ F2 operator*(F2 a, F2 b) { return F2{a.x * b.x, a.y * b.y}; }
__device__ __forceinline__ F2 operator*(float s, F2 a) { return F2{s * a.x, s * a.y}; }

__device__ __forceinline__ F2 ld2(const float* __restrict__ p, int idx) {
    return *reinterpret_cast<const F2*>(p + idx);
}
__device__ __forceinline__ void st_nt2(float* __restrict__ p, F2 v) {
    f2v t = {v.x, v.y};
    __builtin_nontemporal_store(t, reinterpret_cast<f2v*>(p));
}

// ---- spinor loaders ----
struct Direct {                          // global
    const float* re; const float* im; int site;
    __device__ __forceinline__ void load(int s, int c, F2& r, F2& i) const {
        int idx = (s * 3 + c) * VOL + site;
        r = ld2(re, idx); i = ld2(im, idx);
    }
};
struct SRegs {                           // register-held spinor (12 F2 re + im)
    const F2* r; const F2* i;
    __device__ __forceinline__ void load(int s, int c, F2& rr, F2& ii) const {
        rr = r[s * 3 + c]; ii = i[s * 3 + c];
    }
};
struct LDSDirect {                       // lds[24][512], plane (s*3+c)*2+ri
    const float (*L)[512]; int q;
    __device__ __forceinline__ void load(int s, int c, F2& r, F2& i) const {
        int k = (s * 3 + c) * 2;
        r = *reinterpret_cast<const F2*>(&L[k][q]);
        i = *reinterpret_cast<const F2*>(&L[k + 1][q]);
    }
};
struct LDSShift {                        // two arbitrary float indices (x+-1 windows)
    const float (*L)[512]; int i0, i1;
    __device__ __forceinline__ void load(int s, int c, F2& r, F2& i) const {
        int k = (s * 3 + c) * 2;
        r = F2{L[k][i0], L[k][i1]};
        i = F2{L[k + 1][i0], L[k + 1][i1]};
    }
};

// ---- U loaders ----
struct UDirect {
    const float* re; const float* im; int mu, site;
    __device__ __forceinline__ void load(int a, int b, F2& r, F2& i) const {
        int idx = ((a * 3 + b) * 4 + mu) * VOL + site;
        r = ld2(re, idx); i = ld2(im, idx);
    }
};
struct URegs {                           // preloaded 3x3 complex link
    const F2* r; const F2* i;
    __device__ __forceinline__ void load(int a, int b, F2& rr, F2& ii) const {
        rr = r[a * 3 + b]; ii = i[a * 3 + b];
    }
};
struct UShiftRegs {                      // U_x at {x-1, x}: boundary scalar + central.x
    const F2* cr; const F2* ci; const float* blr; const float* bli;
    __device__ __forceinline__ void load(int a, int b, F2& rr, F2& ii) const {
        int e = a * 3 + b;
        rr = F2{blr[e], cr[e].x};
        ii = F2{bli[e], ci[e].x};
    }
};

// One hopping term: project rows 0,1 of (I - S*gamma_mu)psi, multiply by U
// (S=+1) or U^dag (S=-1), reconstruct, accumulate REAL part only into dr.
// Im(chi) needed only for mu=0,2; Re(chi) only for mu=1,3 (compile-time pruned).
template <int MU, int S, class SL, class UL>
__device__ __forceinline__ void hop(const SL& sl, const UL& ul, F2 dr[4][3]) {
    constexpr bool DAG = (S < 0);
    constexpr bool NEEDI = (MU == 0 || MU == 2);
    const float s = (float)S;

    F2 hr[2][3], hi[2][3];
#pragma unroll
    for (int c = 0; c < 3; ++c) {
        F2 p0r, p0i, p1r, p1i, p2r, p2i, p3r, p3i;
        sl.load(0, c, p0r, p0i);
        sl.load(1, c, p1r, p1i);
        sl.load(2, c, p2r, p2i);
        sl.load(3, c, p3r, p3i);
        if (MU == 0) {
            hr[0][c] = p0r + s * p3i;  hi[0][c] = p0i - s * p3r;
            hr[1][c] = p1r + s * p2i;  hi[1][c] = p1i - s * p2r;
        } else if (MU == 1) {
            hr[0][c] = p0r + s * p3r;  hi[0][c] = p0i + s * p3i;
            hr[1][c] = p1r - s * p2r;  hi[1][c] = p1i - s * p2i;
        } else if (MU == 2) {
            hr[0][c] = p0r + s * p2i;  hi[0][c] = p0i - s * p2r;
            hr[1][c] = p1r - s * p3i;  hi[1][c] = p1i + s * p3r;
        } else {
            hr[0][c] = p0r - s * p2r;  hi[0][c] = p0i - s * p2i;
            hr[1][c] = p1r - s * p3r;  hi[1][c] = p1i - s * p3i;
        }
    }

    const float k = KAPPA, ks = KAPPA * s;
#pragma unroll
    for (int a = 0; a < 3; ++a) {
        F2 wr[3], wi[3];
#pragma unroll
        for (int b = 0; b < 3; ++b) {
            F2 r, i;
            if (DAG) { ul.load(b, a, r, i); wi[b] = F2{-i.x, -i.y}; }
            else     { ul.load(a, b, r, i); wi[b] = i; }
            wr[b] = r;
        }
        F2 ar0{0,0}, ar1{0,0}, ai0{0,0}, ai1{0,0};
#pragma unroll
        for (int b = 0; b < 3; ++b) {
            ar0 = ar0 + wr[b] * hr[0][b] - wi[b] * hi[0][b];
            ar1 = ar1 + wr[b] * hr[1][b] - wi[b] * hi[1][b];
            if (NEEDI) {
                ai0 = ai0 + wr[b] * hi[0][b] + wi[b] * hr[0][b];
                ai1 = ai1 + wr[b] * hi[1][b] + wi[b] * hr[1][b];
            }
        }
        dr[0][a] = dr[0][a] - k * ar0;
        dr[1][a] = dr[1][a] - k * ar1;
        if (MU == 0)      { dr[2][a] = dr[2][a] + ks * ai1; dr[3][a] = dr[3][a] + ks * ai0; }
        else if (MU == 1) { dr[2][a] = dr[2][a] + ks * ar1; dr[3][a] = dr[3][a] - ks * ar0; }
        else if (MU == 2) { dr[2][a] = dr[2][a] + ks * ai0; dr[3][a] = dr[3][a] - ks * ai1; }
        else              { dr[2][a] = dr[2][a] + ks * ar0; dr[3][a] = dr[3][a] + ks * ar1; }
    }
}

// Tile x32 x y4 x z4 (512 sites, 256 thr x F2, LDS 48 KB) walking TSTEP=4
// t-slices — EXACT R8 mechanics (no shuffles, no divergent patch loads; R9
// showed those cost more than they save), only the tile shape changes so the
// fat z-spinor-halo (192 B/site, both sides global in R8) becomes interior
// LDS reads: z-halo 192->48, y-halo 12->48, net issued ~774 vs 882 B/site
// under the measured ~25.8 GB/s/CU issued-VMEM wall. Bonus: U_z/U_y bwd
// re-loads now hit addresses just fetched by in-block threads -> L1 hits.
// XCD swizzle: xcd=b&7 owns t in [4k,4k+4); y/z neighbor blocks same XCD.
__global__ __launch_bounds__(256)
void wilson_kernel(const float* __restrict__ src_re, const float* __restrict__ src_im,
                   const float* __restrict__ U_re, const float* __restrict__ U_im,
                   float* __restrict__ out) {
    __shared__ float lds[24][512];

    int b = blockIdx.x;                  // 512 blocks
    int xcd = b & 7;
    int loc = b >> 3;                    // 0..63
    int z0 = (loc & 7) << 2;
    int y0 = (loc >> 3) << 2;
    int t0 = xcd << 2;                   // XCD k walks t in [4k,4k+4)

    int q  = threadIdx.x * 2;            // site index in tile (0..510)
    int lx = q & 31;
    int ly = (q >> 5) & 3;
    int lz = q >> 7;                     // 0..3, wave-uniform
    int y = y0 + ly;
    int z = z0 + lz;
    int base = (z << 10) | (y << 5) | lx;   // site = t<<15 | base

    int rowq = q & ~31;
    int iR0 = rowq | ((lx + 1) & 31), iR1 = rowq | ((lx + 2) & 31);
    int iL0 = rowq | ((lx + 31) & 31);

    // ---- prologue: stage slice t0; dr = central + t-bwd from slice t0-1 ----
    int s0  = (t0 << 15) | base;
    int sm1 = (((t0 + 31) & 31) << 15) | base;
    F2 dr[4][3];
#pragma unroll
    for (int k = 0; k < 12; ++k) {
        F2 r = ld2(src_re, k * VOL + s0);
        F2 i = ld2(src_im, k * VOL + s0);
        *reinterpret_cast<F2*>(&lds[2 * k][q])     = r;
        *reinterpret_cast<F2*>(&lds[2 * k + 1][q]) = i;
        dr[k / 3][k % 3] = r;
    }
    hop<3, -1>(Direct{src_re, src_im, sm1}, UDirect{U_re, U_im, 3, sm1}, dr);
    __syncthreads();

#pragma unroll
    for (int i = 0; i < TSTEP; ++i) {
        int t = t0 + i;
        int s = (t << 15) | base;
        int snext = (((t + 1) & 31) << 15) | base;

        // 1. x hops (spinor from LDS, U_x transient in regs, global bnd scalars)
        {
            int gxm1 = (s & ~31) | ((lx + 31) & 31);
            F2 uxr[9], uxi[9];
            float blr[9], bli[9];
#pragma unroll
            for (int e = 0; e < 9; ++e) {
                uxr[e] = ld2(U_re, (e * 4 + 0) * VOL + s);
                uxi[e] = ld2(U_im, (e * 4 + 0) * VOL + s);
                blr[e] = U_re[(e * 4 + 0) * VOL + gxm1];
                bli[e] = U_im[(e * 4 + 0) * VOL + gxm1];
            }
            hop<0,  1>(LDSShift{lds, iR0, iR1}, URegs{uxr, uxi}, dr);
            hop<0, -1>(LDSShift{lds, iL0, q},   UShiftRegs{uxr, uxi, blr, bli}, dr);
        }

        // 2. y hops (interior LDS, boundary global; U direct like R8)
        {
            int syp = (s & ~(31 << 5)) | (((y + 1)  & 31) << 5);
            int sym = (s & ~(31 << 5)) | (((y + 31) & 31) << 5);
            if (ly < 3) hop<1,  1>(LDSDirect{lds, q + 32}, UDirect{U_re, U_im, 1, s}, dr);
            else        hop<1,  1>(Direct{src_re, src_im, syp}, UDirect{U_re, U_im, 1, s}, dr);
            if (ly > 0) hop<1, -1>(LDSDirect{lds, q - 32}, UDirect{U_re, U_im, 1, sym}, dr);
            else        hop<1, -1>(Direct{src_re, src_im, sym}, UDirect{U_re, U_im, 1, sym}, dr);
        }

        // 3. z hops (interior LDS at q+-128, boundary global; U direct)
        {
            int szp = (s & ~(31 << 10)) | (((z + 1)  & 31) << 10);
            int szm = (s & ~(31 << 10)) | (((z + 31) & 31) << 10);
            if (lz < 3) hop<2,  1>(LDSDirect{lds, q + 128}, UDirect{U_re, U_im, 2, s}, dr);
            else        hop<2,  1>(Direct{src_re, src_im, szp}, UDirect{U_re, U_im, 2, s}, dr);
            if (lz > 0) hop<2, -1>(LDSDirect{lds, q - 128}, UDirect{U_re, U_im, 2, szm}, dr);
            else        hop<2, -1>(Direct{src_re, src_im, szm}, UDirect{U_re, U_im, 2, szm}, dr);
        }

        // 4. next-slice spinor + U_t (low-pressure point)
        F2 nr[12], ni[12];
#pragma unroll
        for (int k = 0; k < 12; ++k) {
            nr[k] = ld2(src_re, k * VOL + snext);
            ni[k] = ld2(src_im, k * VOL + snext);
        }
        F2 utr[9], uti[9];
#pragma unroll
        for (int e = 0; e < 9; ++e) {
            utr[e] = ld2(U_re, (e * 4 + 3) * VOL + s);
            uti[e] = ld2(U_im, (e * 4 + 3) * VOL + s);
        }

        // 5. t-fwd from next-slice regs; store; dr dead after
        hop<3,  1>(SRegs{nr, ni}, URegs{utr, uti}, dr);
#pragma unroll
        for (int ss = 0; ss < 4; ++ss)
#pragma unroll
            for (int c = 0; c < 3; ++c)
                st_nt2(out + (ss * 3 + c) * VOL + s, dr[ss][c]);

        // 6. rebuild dr for slice t+1 (central + t-bwd via cur LDS + same U_t)
        if (i < TSTEP - 1) {
#pragma unroll
            for (int k = 0; k < 12; ++k) dr[k / 3][k % 3] = nr[k];
            hop<3, -1>(LDSDirect{lds, q}, URegs{utr, uti}, dr);
            __syncthreads();
#pragma unroll
            for (int k = 0; k < 12; ++k) {
                *reinterpret_cast<F2*>(&lds[2 * k][q])     = nr[k];
                *reinterpret_cast<F2*>(&lds[2 * k + 1][q]) = ni[k];
            }
            __syncthreads();
        }
    }
}

extern "C" void kernel_launch(void* const* d_in, const int* in_sizes, int n_in,
                              void* d_out, int out_size, void* d_ws, size_t ws_size,
                              hipStream_t stream) {
    const float* src_re = (const float*)d_in[0];
    const float* src_im = (const float*)d_in[1];
    const float* U_re   = (const float*)d_in[2];
    const float* U_im   = (const float*)d_in[3];
    float* out = (float*)d_out;

    dim3 block(256);
    dim3 grid(VOL / 2 / 256 / TSTEP);    // 512 blocks
    wilson_kernel<<<grid, block, 0, stream>>>(src_re, src_im, U_re, U_im, out);
}

// Round 11
// 145.267 us; speedup vs baseline: 1.3252x; 1.3252x over previous
//
#include <hip/hip_runtime.h>

constexpr int VOL = 32 * 32 * 32 * 32;   // 1048576 sites
constexpr float KAPPA = 0.1f;            // kappa/u0
constexpr int TSTEP = 4;                 // t-slices walked per block

struct alignas(8) F2 { float x, y; };
using f2v = __attribute__((ext_vector_type(2))) float;

__device__ __forceinline__ F2 operator+(F2 a, F2 b) { return F2{a.x + b.x, a.y + b.y}; }
__device__ __forceinline__ F2 operator-(F2 a, F2 b) { return F2{a.x - b.x, a.y - b.y}; }
__device__ __forceinline__ F2 operator*(F2 a, F2 b) { return F2{a.x * b.x, a.y * b.y}; }
__device__ __forceinline__ F2 operator*(float s, F2 a) { return F2{s * a.x, s * a.y}; }

__device__ __forceinline__ F2 ld2(const float* __restrict__ p, int idx) {
    return *reinterpret_cast<const F2*>(p + idx);
}
__device__ __forceinline__ void st_nt2(float* __restrict__ p, F2 v) {
    f2v t = {v.x, v.y};
    __builtin_nontemporal_store(t, reinterpret_cast<f2v*>(p));
}

// ---- spinor loaders ----
struct Direct {                          // global
    const float* re; const float* im; int site;
    __device__ __forceinline__ void load(int s, int c, F2& r, F2& i) const {
        int idx = (s * 3 + c) * VOL + site;
        r = ld2(re, idx); i = ld2(im, idx);
    }
};
struct SRegs {                           // register-held spinor (12 F2 re + im)
    const F2* r; const F2* i;
    __device__ __forceinline__ void load(int s, int c, F2& rr, F2& ii) const {
        rr = r[s * 3 + c]; ii = i[s * 3 + c];
    }
};
struct LDSDirect {                       // lds[24][512], plane (s*3+c)*2+ri
    const float (*L)[512]; int q;
    __device__ __forceinline__ void load(int s, int c, F2& r, F2& i) const {
        int k = (s * 3 + c) * 2;
        r = *reinterpret_cast<const F2*>(&L[k][q]);
        i = *reinterpret_cast<const F2*>(&L[k + 1][q]);
    }
};
struct LDSShift {                        // two arbitrary float indices (x+-1 windows)
    const float (*L)[512]; int i0, i1;
    __device__ __forceinline__ void load(int s, int c, F2& r, F2& i) const {
        int k = (s * 3 + c) * 2;
        r = F2{L[k][i0], L[k][i1]};
        i = F2{L[k + 1][i0], L[k + 1][i1]};
    }
};

// ---- U loaders ----
struct UDirect {
    const float* re; const float* im; int mu, site;
    __device__ __forceinline__ void load(int a, int b, F2& r, F2& i) const {
        int idx = ((a * 3 + b) * 4 + mu) * VOL + site;
        r = ld2(re, idx); i = ld2(im, idx);
    }
};
struct URegs {                           // preloaded 3x3 complex link
    const F2* r; const F2* i;
    __device__ __forceinline__ void load(int a, int b, F2& rr, F2& ii) const {
        rr = r[a * 3 + b]; ii = i[a * 3 + b];
    }
};
struct UShiftRegs {                      // U_x at {x-1, x}: boundary scalar + central.x
    const F2* cr; const F2* ci; const float* blr; const float* bli;
    __device__ __forceinline__ void load(int a, int b, F2& rr, F2& ii) const {
        int e = a * 3 + b;
        rr = F2{blr[e], cr[e].x};
        ii = F2{bli[e], ci[e].x};
    }
};

// One hopping term: project rows 0,1 of (I - S*gamma_mu)psi, multiply by U
// (S=+1) or U^dag (S=-1), reconstruct, accumulate REAL part only into dr.
// Im(chi) needed only for mu=0,2; Re(chi) only for mu=1,3 (compile-time pruned).
template <int MU, int S, class SL, class UL>
__device__ __forceinline__ void hop(const SL& sl, const UL& ul, F2 dr[4][3]) {
    constexpr bool DAG = (S < 0);
    constexpr bool NEEDI = (MU == 0 || MU == 2);
    const float s = (float)S;

    F2 hr[2][3], hi[2][3];
#pragma unroll
    for (int c = 0; c < 3; ++c) {
        F2 p0r, p0i, p1r, p1i, p2r, p2i, p3r, p3i;
        sl.load(0, c, p0r, p0i);
        sl.load(1, c, p1r, p1i);
        sl.load(2, c, p2r, p2i);
        sl.load(3, c, p3r, p3i);
        if (MU == 0) {
            hr[0][c] = p0r + s * p3i;  hi[0][c] = p0i - s * p3r;
            hr[1][c] = p1r + s * p2i;  hi[1][c] = p1i - s * p2r;
        } else if (MU == 1) {
            hr[0][c] = p0r + s * p3r;  hi[0][c] = p0i + s * p3i;
            hr[1][c] = p1r - s * p2r;  hi[1][c] = p1i - s * p2i;
        } else if (MU == 2) {
            hr[0][c] = p0r + s * p2i;  hi[0][c] = p0i - s * p2r;
            hr[1][c] = p1r - s * p3i;  hi[1][c] = p1i + s * p3r;
        } else {
            hr[0][c] = p0r - s * p2r;  hi[0][c] = p0i - s * p2i;
            hr[1][c] = p1r - s * p3r;  hi[1][c] = p1i - s * p3i;
        }
    }

    const float k = KAPPA, ks = KAPPA * s;
#pragma unroll
    for (int a = 0; a < 3; ++a) {
        F2 wr[3], wi[3];
#pragma unroll
        for (int b = 0; b < 3; ++b) {
            F2 r, i;
            if (DAG) { ul.load(b, a, r, i); wi[b] = F2{-i.x, -i.y}; }
            else     { ul.load(a, b, r, i); wi[b] = i; }
            wr[b] = r;
        }
        F2 ar0{0,0}, ar1{0,0}, ai0{0,0}, ai1{0,0};
#pragma unroll
        for (int b = 0; b < 3; ++b) {
            ar0 = ar0 + wr[b] * hr[0][b] - wi[b] * hi[0][b];
            ar1 = ar1 + wr[b] * hr[1][b] - wi[b] * hi[1][b];
            if (NEEDI) {
                ai0 = ai0 + wr[b] * hi[0][b] + wi[b] * hr[0][b];
                ai1 = ai1 + wr[b] * hi[1][b] + wi[b] * hr[1][b];
            }
        }
        dr[0][a] = dr[0][a] - k * ar0;
        dr[1][a] = dr[1][a] - k * ar1;
        if (MU == 0)      { dr[2][a] = dr[2][a] + ks * ai1; dr[3][a] = dr[3][a] + ks * ai0; }
        else if (MU == 1) { dr[2][a] = dr[2][a] + ks * ar1; dr[3][a] = dr[3][a] - ks * ar0; }
        else if (MU == 2) { dr[2][a] = dr[2][a] + ks * ai0; dr[3][a] = dr[3][a] - ks * ai1; }
        else              { dr[2][a] = dr[2][a] + ks * ar0; dr[3][a] = dr[3][a] + ks * ar1; }
    }
}

// Tile x32 x y8 x z2 (512 sites, 256 thr x F2 x-pairs, LDS 48 KB), TSTEP=4
// t-walk. Minimum delta from R8 (y16z1, 142.7 us): the z-pair gives every
// site exactly ONE z-side from LDS (z-halo 192->96 B/site); lz = tid>>7 is
// WAVE-UNIFORM (waves 0-1 z0, waves 2-3 z0+1) -> scalar branch, no exec-mask
// divergence, unlike R10's y4z4 whose 50% divergent edge rows spilled.
// y edges 2/8 rows (R8 pattern). ~798 B/site vs R8's 882 under the measured
// ~10.75 B/cyc/CU issued-VMEM wall. No shuffles (R9 lesson), no U staging.
// XCD swizzle: xcd=b&7 owns t in [4k,4k+4); y/z neighbor blocks same XCD.
__global__ __launch_bounds__(256)
void wilson_kernel(const float* __restrict__ src_re, const float* __restrict__ src_im,
                   const float* __restrict__ U_re, const float* __restrict__ U_im,
                   float* __restrict__ out) {
    __shared__ float lds[24][512];

    int b = blockIdx.x;                  // 512 blocks
    int xcd = b & 7;
    int loc = b >> 3;                    // 0..63
    int z0 = (loc & 15) << 1;            // z-pair base
    int y0 = (loc >> 4) << 3;            // y-octet base
    int t0 = xcd << 2;                   // XCD k walks t in [4k,4k+4)

    int q  = threadIdx.x * 2;            // site index in tile (0..510)
    int lx = q & 31;
    int ly = (q >> 5) & 7;
    int lz = q >> 8;                     // 0 (tid<128) or 1 (tid>=128), wave-uniform
    int y = y0 + ly;
    int z = z0 + lz;
    int base = (z << 10) | (y << 5) | lx;   // site = t<<15 | base

    int rowq = q & ~31;
    int iR0 = rowq | ((lx + 1) & 31), iR1 = rowq | ((lx + 2) & 31);
    int iL0 = rowq | ((lx + 31) & 31);

    // ---- prologue: stage slice t0; dr = central + t-bwd from slice t0-1 ----
    int s0  = (t0 << 15) | base;
    int sm1 = (((t0 + 31) & 31) << 15) | base;
    F2 dr[4][3];
#pragma unroll
    for (int k = 0; k < 12; ++k) {
        F2 r = ld2(src_re, k * VOL + s0);
        F2 i = ld2(src_im, k * VOL + s0);
        *reinterpret_cast<F2*>(&lds[2 * k][q])     = r;
        *reinterpret_cast<F2*>(&lds[2 * k + 1][q]) = i;
        dr[k / 3][k % 3] = r;
    }
    hop<3, -1>(Direct{src_re, src_im, sm1}, UDirect{U_re, U_im, 3, sm1}, dr);
    __syncthreads();

#pragma unroll
    for (int i = 0; i < TSTEP; ++i) {
        int t = t0 + i;
        int s = (t << 15) | base;
        int snext = (((t + 1) & 31) << 15) | base;

        // 1. x hops (spinor from LDS, U_x transient in regs, global bnd scalars)
        {
            int gxm1 = (s & ~31) | ((lx + 31) & 31);
            F2 uxr[9], uxi[9];
            float blr[9], bli[9];
#pragma unroll
            for (int e = 0; e < 9; ++e) {
                uxr[e] = ld2(U_re, (e * 4 + 0) * VOL + s);
                uxi[e] = ld2(U_im, (e * 4 + 0) * VOL + s);
                blr[e] = U_re[(e * 4 + 0) * VOL + gxm1];
                bli[e] = U_im[(e * 4 + 0) * VOL + gxm1];
            }
            hop<0,  1>(LDSShift{lds, iR0, iR1}, URegs{uxr, uxi}, dr);
            hop<0, -1>(LDSShift{lds, iL0, q},   UShiftRegs{uxr, uxi, blr, bli}, dr);
        }

        // 2. y hops (interior LDS, boundary global; U direct like R8)
        {
            int syp = (s & ~(31 << 5)) | (((y + 1)  & 31) << 5);
            int sym = (s & ~(31 << 5)) | (((y + 31) & 31) << 5);
            if (ly < 7) hop<1,  1>(LDSDirect{lds, q + 32}, UDirect{U_re, U_im, 1, s}, dr);
            else        hop<1,  1>(Direct{src_re, src_im, syp}, UDirect{U_re, U_im, 1, s}, dr);
            if (ly > 0) hop<1, -1>(LDSDirect{lds, q - 32}, UDirect{U_re, U_im, 1, sym}, dr);
            else        hop<1, -1>(Direct{src_re, src_im, sym}, UDirect{U_re, U_im, 1, sym}, dr);
        }

        // 3. z hops: one side LDS per site, wave-uniform lz branch
        {
            int szp = (s & ~(31 << 10)) | (((z + 1)  & 31) << 10);
            int szm = (s & ~(31 << 10)) | (((z + 31) & 31) << 10);
            if (lz == 0) {
                hop<2,  1>(LDSDirect{lds, q + 256}, UDirect{U_re, U_im, 2, s}, dr);
                hop<2, -1>(Direct{src_re, src_im, szm}, UDirect{U_re, U_im, 2, szm}, dr);
            } else {
                hop<2,  1>(Direct{src_re, src_im, szp}, UDirect{U_re, U_im, 2, s}, dr);
                hop<2, -1>(LDSDirect{lds, q - 256}, UDirect{U_re, U_im, 2, szm}, dr);
            }
        }

        // 4. next-slice spinor + U_t (low-pressure point)
        F2 nr[12], ni[12];
#pragma unroll
        for (int k = 0; k < 12; ++k) {
            nr[k] = ld2(src_re, k * VOL + snext);
            ni[k] = ld2(src_im, k * VOL + snext);
        }
        F2 utr[9], uti[9];
#pragma unroll
        for (int e = 0; e < 9; ++e) {
            utr[e] = ld2(U_re, (e * 4 + 3) * VOL + s);
            uti[e] = ld2(U_im, (e * 4 + 3) * VOL + s);
        }

        // 5. t-fwd from next-slice regs; store; dr dead after
        hop<3,  1>(SRegs{nr, ni}, URegs{utr, uti}, dr);
#pragma unroll
        for (int ss = 0; ss < 4; ++ss)
#pragma unroll
            for (int c = 0; c < 3; ++c)
                st_nt2(out + (ss * 3 + c) * VOL + s, dr[ss][c]);

        // 6. rebuild dr for slice t+1 (central + t-bwd via cur LDS + same U_t)
        if (i < TSTEP - 1) {
#pragma unroll
            for (int k = 0; k < 12; ++k) dr[k / 3][k % 3] = nr[k];
            hop<3, -1>(LDSDirect{lds, q}, URegs{utr, uti}, dr);
            __syncthreads();
#pragma unroll
            for (int k = 0; k < 12; ++k) {
                *reinterpret_cast<F2*>(&lds[2 * k][q])     = nr[k];
                *reinterpret_cast<F2*>(&lds[2 * k + 1][q]) = ni[k];
            }
            __syncthreads();
        }
    }
}

extern "C" void kernel_launch(void* const* d_in, const int* in_sizes, int n_in,
                              void* d_out, int out_size, void* d_ws, size_t ws_size,
                              hipStream_t stream) {
    const float* src_re = (const float*)d_in[0];
    const float* src_im = (const float*)d_in[1];
    const float* U_re   = (const float*)d_in[2];
    const float* U_im   = (const float*)d_in[3];
    float* out = (float*)d_out;

    dim3 block(256);
    dim3 grid(VOL / 2 / 256 / TSTEP);    // 512 blocks
    wilson_kernel<<<grid, block, 0, stream>>>(src_re, src_im, U_re, U_im, out);
}